// Round 2
// baseline (395.349 us; speedup 1.0000x reference)
//
#include <hip/hip_runtime.h>

// Recurrent ALIF 2D layer, forward only.
// x: (B=8, T=64, H=16, W=16, F=256) f32, w_rec: (256,256) f32.
//
// Sites (b,h,w) are independent (recurrence couples only the feature dim).
// prev_s in {0,1} exactly => rec = sum of active rows of W, and summing in
// increasing k is bit-identical to a sequential-k fp32 FMA dot (verified:
// absmax 0.0 in R0). The rec += chain below stays in increasing-k program
// order; only loads are reordered (safe).
//
// One block (256 threads) per site; thread = feature; T-loop in-kernel.
// R1 changes vs R0 (VALU-issue bound, 54% busy):
//  - list stores pre-shifted byte offsets (k<<10): no shift in hot loop
//  - gather addresses = uniform SGPR base (w_rec) + 32-bit voffset (1 v_add)
//  - unroll-by-4 with int4 (ds_read_b128) list reads
//  - per-wave ballot COUNTS in LDS (one int4 read) instead of 4 u64 masks;
//    intra-wave prefix comes from the in-register ballot mask
//  - trailing barrier dropped: cnt writes (t+1, pre-sync1) vs cnt reads (t,
//    pre-sync2) are ordered by sync2(t); list writes (t+1, post-sync1(t+1))
//    vs list reads (t, gather) are ordered by sync1(t+1). Disjoint arrays.

#define FDIM 256
#define TSTEPS 64
#define HWDIM 256  // H*W

__global__ __launch_bounds__(256, 8) void alif_kernel(
    const float* __restrict__ x,
    const float* __restrict__ w_rec,
    const float* __restrict__ hp_d_p,
    const float* __restrict__ hp_adp_p,
    const float* __restrict__ hp_beta_p,
    float* __restrict__ out)
{
    const int tid  = threadIdx.x;   // feature index f
    const int blk  = blockIdx.x;    // site index: b*HW + hw
    const int wave = tid >> 6;
    const int lane = tid & 63;

    const float d    = hp_d_p[0];
    const float adp  = hp_adp_p[0];
    const float beta = hp_beta_p[0];

    __shared__ __align__(16) int list[FDIM];  // pre-shifted byte offsets k<<10
    __shared__ __align__(16) int cnt[4];      // per-wave spike counts

    const int b  = blk >> 8;
    const int hw = blk & 255;
    // flat index of x[b, t=0, hw, f]; layout (B, T, H, W, F)
    size_t idx = (size_t)b * TSTEPS * (HWDIM * FDIM) + (size_t)hw * FDIM + tid;
    const size_t tstride = (size_t)HWDIM * FDIM;  // 65536

    const int fbyte = tid << 2;               // column byte offset within a row
    const char* wb = (const char*)w_rec;      // wave-uniform base -> SGPR pair

    float v = 0.f, th = 0.f, s = 0.f;

    for (int t = 0; t < TSTEPS; ++t) {
        float xt = x[idx];  // issued early, consumed after gather

        // ---- compact active spike indices (increasing-k order) ----
        unsigned long long m = __ballot(s != 0.f);
        if (lane == 0) cnt[wave] = __popcll(m);
        __syncthreads();
        int4 c4 = *(const int4*)cnt;          // one ds_read_b128
        int base  = (wave > 0 ? c4.x : 0) + (wave > 1 ? c4.y : 0)
                  + (wave > 2 ? c4.z : 0);
        int total = c4.x + c4.y + c4.z + c4.w;
        if (s != 0.f) {
            int pos = base + __popcll(m & ((1ull << lane) - 1ull));
            list[pos] = tid << 10;            // byte offset of row k
        }
        __syncthreads();

        // ---- rec_f = sum over active k (increasing k) of W[k][f] ----
        float rec = 0.f;
        int i = 0;
        for (; i + 4 <= total; i += 4) {
            int4 ko = *(const int4*)&list[i];             // ds_read_b128
            float w0 = *(const float*)(wb + (ko.x + fbyte));
            float w1 = *(const float*)(wb + (ko.y + fbyte));
            float w2 = *(const float*)(wb + (ko.z + fbyte));
            float w3 = *(const float*)(wb + (ko.w + fbyte));
            rec += w0; rec += w1; rec += w2; rec += w3;   // order preserved
        }
        for (; i < total; ++i) {
            int ko = list[i];
            rec += *(const float*)(wb + (ko + fbyte));
        }

        // ---- elementwise ALIF update ----
        th = fmaf(th, adp, s * beta);
        float vn  = fmaf(v, d, xt) + rec;
        float vth = 0.5f + th;
        float sn  = (vn - vth) > 0.f ? 1.f : 0.f;
        v = vn - sn * vth;
        s = sn;
        out[idx] = sn;

        idx += tstride;
        // no trailing barrier (see header comment)
    }
}

extern "C" void kernel_launch(void* const* d_in, const int* in_sizes, int n_in,
                              void* d_out, int out_size, void* d_ws, size_t ws_size,
                              hipStream_t stream) {
    const float* x       = (const float*)d_in[0];
    const float* w_rec   = (const float*)d_in[1];
    const float* hp_d    = (const float*)d_in[2];
    const float* hp_adp  = (const float*)d_in[3];
    const float* hp_beta = (const float*)d_in[4];
    // d_in[5] = hp_alpha: unused in forward
    float* out = (float*)d_out;

    // 2048 sites (8*16*16), one block each = 8 blocks/CU on 256 CUs.
    alif_kernel<<<2048, 256, 0, stream>>>(x, w_rec, hp_d, hp_adp, hp_beta, out);
}